// Round 2
// baseline (405.360 us; speedup 1.0000x reference)
//
#include <hip/hip_runtime.h>
#include <hip/hip_bf16.h>

// Problem constants
#define N_TOK   16384      // B*T
#define HDIM    2048       // H*d_h
#define NH      16
#define DH      128
#define NPAIRS  120
#define KCHUNKS 8
#define KC_LEN  (N_TOK / KCHUNKS)   // 2048
#define BK      64

// Workspace layout (bytes)
#define SUM_OFF    0u
#define SUMSQ_OFF  8192u
#define MU_OFF     16384u
#define RINV_OFF   24576u
#define LSUM_OFF   32768u
#define PC_OFF     36864u                     // 120*128*128 f32 = 7,864,320 B
#define XT_OFF     7901184u                   // 2048*16384 bf16 = 67,108,864 B
// total ws use: ~71.5 MB (same as R0, which fit)

typedef short   bf16x8 __attribute__((ext_vector_type(8)));   // 8 bf16 = 4 VGPRs
typedef float   f32x4  __attribute__((ext_vector_type(4)));

__device__ __forceinline__ unsigned short f2bf(float f) {
    unsigned int u = __float_as_uint(f);
    u += 0x7fffu + ((u >> 16) & 1u);              // round-to-nearest-even
    return (unsigned short)(u >> 16);
}

// ---------------------------------------------------------------- pass 1: fused stats + transpose + bf16 cast
// Single read of X (134 MB). Stats on raw X (exact, fp32 via atomics);
// Xt holds RAW bf16 (normalization folded into pair_reduce epilogue).
__global__ void stats_transpose_kernel(const float* __restrict__ X,
                                       float* __restrict__ sum, float* __restrict__ sumsq,
                                       unsigned short* __restrict__ Xt) {
    __shared__ float tile[64][65];                // +1 pad
    int c0 = blockIdx.x * 64;                     // gridDim.x = 32
    int n0 = blockIdx.y * 64;                     // gridDim.y = 256
    int tx = threadIdx.x;
    int l  = tx & 63;

    int c4 = (tx & 15) * 4;                       // 4 consecutive columns per thread
    int rb = tx >> 4;                             // 0..15
    float4 s  = make_float4(0.f, 0.f, 0.f, 0.f);
    float4 ss = make_float4(0.f, 0.f, 0.f, 0.f);
    #pragma unroll
    for (int it = 0; it < 4; ++it) {
        int r = rb + it * 16;
        float4 x = *(const float4*)(X + (size_t)(n0 + r) * HDIM + c0 + c4);
        s.x += x.x; s.y += x.y; s.z += x.z; s.w += x.w;
        ss.x += x.x * x.x; ss.y += x.y * x.y; ss.z += x.z * x.z; ss.w += x.w * x.w;
        tile[r][c4 + 0] = x.x; tile[r][c4 + 1] = x.y;
        tile[r][c4 + 2] = x.z; tile[r][c4 + 3] = x.w;
    }
    // wave-level: lanes l, l+16, l+32, l+48 share the same columns
    #pragma unroll
    for (int o = 32; o >= 16; o >>= 1) {
        s.x += __shfl_down(s.x, o);  s.y += __shfl_down(s.y, o);
        s.z += __shfl_down(s.z, o);  s.w += __shfl_down(s.w, o);
        ss.x += __shfl_down(ss.x, o); ss.y += __shfl_down(ss.y, o);
        ss.z += __shfl_down(ss.z, o); ss.w += __shfl_down(ss.w, o);
    }
    if ((l >> 4) == 0) {                          // lanes 0..15 of each wave
        int c = c0 + l * 4;
        atomicAdd(&sum[c + 0], s.x);  atomicAdd(&sum[c + 1], s.y);
        atomicAdd(&sum[c + 2], s.z);  atomicAdd(&sum[c + 3], s.w);
        atomicAdd(&sumsq[c + 0], ss.x); atomicAdd(&sumsq[c + 1], ss.y);
        atomicAdd(&sumsq[c + 2], ss.z); atomicAdd(&sumsq[c + 3], ss.w);
    }
    __syncthreads();
    #pragma unroll
    for (int it = 0; it < 4; ++it) {
        int lin = it * 256 + tx;                  // 1024 items of 4 n-elems
        int g = lin & 15, c = lin >> 4;           // c in 0..63
        ushort4 o;
        o.x = f2bf(tile[g * 4 + 0][c]);
        o.y = f2bf(tile[g * 4 + 1][c]);
        o.z = f2bf(tile[g * 4 + 2][c]);
        o.w = f2bf(tile[g * 4 + 3][c]);
        *(ushort4*)(Xt + (size_t)(c0 + c) * N_TOK + n0 + g * 4) = o;
    }
}

// ---------------------------------------------------------------- pass 2: mu / rinv
__global__ void finalize_kernel(const float* __restrict__ sum, const float* __restrict__ sumsq,
                                float* __restrict__ mu, float* __restrict__ rinv) {
    int c = blockIdx.x * 256 + threadIdx.x;       // grid 8 x 256 = 2048
    float m = sum[c] * (1.f / (float)N_TOK);
    float var = (sumsq[c] - (float)N_TOK * m * m) * (1.f / (float)(N_TOK - 1));
    var = fmaxf(var, 0.f);
    mu[c]   = m;
    rinv[c] = 1.f / (sqrtf(var) + 1e-8f);
}

// ---------------------------------------------------------------- pass 3: pairwise raw Gram via MFMA
__device__ __forceinline__ void gload16(const void* gsrc, void* ldst) {
    __builtin_amdgcn_global_load_lds(
        (const __attribute__((address_space(1))) unsigned int*)gsrc,
        (__attribute__((address_space(3))) unsigned int*)ldst,
        16, 0, 0);
}

__global__ __launch_bounds__(256, 4)
void gram_kernel(const unsigned short* __restrict__ Xt, float* __restrict__ pairC) {
    const int kc = blockIdx.x;                    // K-chunk 0..7
    const int p  = blockIdx.y;                    // pair 0..119
    int i = 0, rem = p;
    while (rem >= NH - 1 - i) { rem -= NH - 1 - i; ++i; }
    const int j = i + 1 + rem;

    __shared__ alignas(16) unsigned short ldsA[128 * BK];   // 16 KB
    __shared__ alignas(16) unsigned short ldsB[128 * BK];   // 16 KB

    const int tx = threadIdx.x;
    const int w  = tx >> 6, l = tx & 63;
    const int wm = w >> 1, wn = w & 1;            // 2x2 wave grid over 128x128
    const int l15 = l & 15, quad = l >> 4;

    // Staging: tile = 128 rows x 8 chunks of 16B; XOR swizzle at SOURCE address
    unsigned int goff[4];
    int ldsOff[4];
    #pragma unroll
    for (int s = 0; s < 4; ++s) {
        int cfl = s * 256 + tx;
        int r = cfl >> 3, cl = cfl & 7;
        int cg = cl ^ (r & 7);
        goff[s]   = (unsigned int)r * (N_TOK * 2) + (unsigned int)cg * 16;
        ldsOff[s] = s * 4096 + w * 1024;          // wave-uniform LDS base per issue
    }
    const char* Abase = (const char*)(Xt + (size_t)i * DH * N_TOK);
    const char* Bbase = (const char*)(Xt + (size_t)j * DH * N_TOK);

    f32x4 acc[4][4];
    #pragma unroll
    for (int mi = 0; mi < 4; ++mi)
        #pragma unroll
        for (int ni = 0; ni < 4; ++ni)
            acc[mi][ni] = (f32x4){0.f, 0.f, 0.f, 0.f};

    int k0 = kc * KC_LEN;
    const int sw = (l15 & 7);
    for (int kt = 0; kt < KC_LEN / BK; ++kt, k0 += BK) {
        size_t kbyte = (size_t)k0 * 2;
        #pragma unroll
        for (int s = 0; s < 4; ++s)
            gload16(Abase + goff[s] + kbyte, (char*)ldsA + ldsOff[s]);
        #pragma unroll
        for (int s = 0; s < 4; ++s)
            gload16(Bbase + goff[s] + kbyte, (char*)ldsB + ldsOff[s]);
        __syncthreads();

        #pragma unroll
        for (int kh = 0; kh < 2; ++kh) {
            const int q0 = kh * 4 + quad;
            const int c8 = q0 ^ sw;
            bf16x8 a[4], b[4];
            #pragma unroll
            for (int mi = 0; mi < 4; ++mi) {
                int r = wm * 64 + mi * 16 + l15;
                a[mi] = *(const bf16x8*)(ldsA + (r * 8 + c8) * 8);
            }
            #pragma unroll
            for (int ni = 0; ni < 4; ++ni) {
                int r = wn * 64 + ni * 16 + l15;
                b[ni] = *(const bf16x8*)(ldsB + (r * 8 + c8) * 8);
            }
            #pragma unroll
            for (int mi = 0; mi < 4; ++mi)
                #pragma unroll
                for (int ni = 0; ni < 4; ++ni)
                    acc[mi][ni] = __builtin_amdgcn_mfma_f32_16x16x32_bf16(
                        a[mi], b[ni], acc[mi][ni], 0, 0, 0);
        }
        __syncthreads();
    }

    // Epilogue: partial raw Gram -> atomic accumulate (8 contenders/address)
    float* pc = pairC + (size_t)p * (DH * DH);
    #pragma unroll
    for (int mi = 0; mi < 4; ++mi)
        #pragma unroll
        for (int ni = 0; ni < 4; ++ni)
            #pragma unroll
            for (int r = 0; r < 4; ++r) {
                int row = wm * 64 + mi * 16 + quad * 4 + r;  // d (head-i dim)
                int col = wn * 64 + ni * 16 + l15;           // e (head-j dim)
                atomicAdd(&pc[row * DH + col], acc[mi][ni][r]);
            }
}

// ---------------------------------------------------------------- pass 4: per-pair loss w/ normalization correction
__global__ void pair_reduce_kernel(const float* __restrict__ pairC, const float* __restrict__ G,
                                   const float* __restrict__ mu, const float* __restrict__ rinv,
                                   float* __restrict__ lsum) {
    int p = blockIdx.x;
    int i = 0, rem = p;
    while (rem >= NH - 1 - i) { rem -= NH - 1 - i; ++i; }
    int j = i + 1 + rem;
    __shared__ float smui[DH], smuj[DH], sri[DH], srj[DH];
    if (threadIdx.x < DH) {
        smui[threadIdx.x] = mu[i * DH + threadIdx.x];
        smuj[threadIdx.x] = mu[j * DH + threadIdx.x];
        sri[threadIdx.x]  = rinv[i * DH + threadIdx.x];
        srj[threadIdx.x]  = rinv[j * DH + threadIdx.x];
    }
    __syncthreads();
    const float invN = 1.f / (float)N_TOK;
    const float* pc = pairC + (size_t)p * (DH * DH);
    float s = 0.f;
    for (int idx = threadIdx.x; idx < DH * DH; idx += 256) {
        int d = idx >> 7, e = idx & 127;
        float cn = (pc[idx] * invN - smui[d] * smuj[e]) * sri[d] * srj[e];
        float diff = cn - ((d == e) ? 1.f : 0.f);
        s += diff * diff;
    }
    for (int o = 32; o; o >>= 1) s += __shfl_down(s, o);
    __shared__ float red[4];
    if ((threadIdx.x & 63) == 0) red[threadIdx.x >> 6] = s;
    __syncthreads();
    if (threadIdx.x == 0) {
        float t = red[0] + red[1] + red[2] + red[3];
        float x = -15.99f * (G[i * NH + j] - 0.0f);
        float sp = (x > 20.f) ? x : log1pf(expf(x));
        float wgt = 0.929f + (1.f - 0.929f) * sp;
        atomicAdd(lsum, wgt * t);
    }
}

__global__ void final_kernel(const float* __restrict__ lsum, float* __restrict__ out) {
    if (threadIdx.x == 0) out[0] = lsum[0] * (1.f / (float)NPAIRS);
}

// ---------------------------------------------------------------- launcher
extern "C" void kernel_launch(void* const* d_in, const int* in_sizes, int n_in,
                              void* d_out, int out_size, void* d_ws, size_t ws_size,
                              hipStream_t stream) {
    const float* X = (const float*)d_in[0];
    const float* G = (const float*)d_in[1];
    float* out = (float*)d_out;
    char* ws = (char*)d_ws;

    float*          sum   = (float*)(ws + SUM_OFF);
    float*          sumsq = (float*)(ws + SUMSQ_OFF);
    float*          mu    = (float*)(ws + MU_OFF);
    float*          rinv  = (float*)(ws + RINV_OFF);
    float*          lsum  = (float*)(ws + LSUM_OFF);
    float*          pairC = (float*)(ws + PC_OFF);
    unsigned short* Xt    = (unsigned short*)(ws + XT_OFF);

    hipMemsetAsync(ws + SUM_OFF, 0, 16384, stream);                     // sum+sumsq
    hipMemsetAsync(ws + LSUM_OFF, 0, 4, stream);
    hipMemsetAsync(ws + PC_OFF, 0, (size_t)NPAIRS * DH * DH * 4, stream);

    stats_transpose_kernel<<<dim3(32, 256), 256, 0, stream>>>(X, sum, sumsq, Xt);
    finalize_kernel<<<8, 256, 0, stream>>>(sum, sumsq, mu, rinv);
    gram_kernel<<<dim3(KCHUNKS, NPAIRS), 256, 0, stream>>>(Xt, pairC);
    pair_reduce_kernel<<<NPAIRS, 256, 0, stream>>>(pairC, G, mu, rinv, lsum);
    final_kernel<<<1, 64, 0, stream>>>(lsum, out);
}

// Round 3
// 316.322 us; speedup vs baseline: 1.2815x; 1.2815x over previous
//
#include <hip/hip_runtime.h>
#include <hip/hip_bf16.h>

// Problem constants
#define N_TOK   16384      // B*T
#define HDIM    2048       // H*d_h
#define NH      16
#define DH      128
#define NPAIRS  120
#define KCHUNKS 8
#define NKT     (N_TOK / 64)            // 256 k-tiles of 64 tokens
#define KT_PER_CHUNK (NKT / KCHUNKS)    // 32
#define PANEL_BYTES 16384               // 128 c-rows x 64 tokens x 2B

// Workspace layout (bytes) — total 75,010,048 B (same as R0, known to fit)
#define SUM_OFF    0u
#define SUMSQ_OFF  8192u
#define MU_OFF     16384u
#define RINV_OFF   24576u
#define LSUM_OFF   32768u
#define PC_OFF     36864u                     // 120*128*128 f32 = 7,864,320 B
#define XT_OFF     7901184u                   // 2048*16384 bf16 = 67,108,864 B

typedef short   bf16x8 __attribute__((ext_vector_type(8)));   // 8 bf16 = 4 VGPRs
typedef float   f32x4  __attribute__((ext_vector_type(4)));

__device__ __forceinline__ unsigned short f2bf(float f) {
    unsigned int u = __float_as_uint(f);
    u += 0x7fffu + ((u >> 16) & 1u);              // round-to-nearest-even
    return (unsigned short)(u >> 16);
}

// ---------------------------------------------------------------- pass 1: fused stats + panelized transpose + bf16
// Block = one 16 KB panel: head h, tokens n0..n0+63, all 128 head-dims.
// Reads X contiguously (512 B/row segments); writes ONE contiguous 16 KB panel.
__global__ __launch_bounds__(256)
void stats_transpose_kernel(const float* __restrict__ X,
                            float* __restrict__ sum, float* __restrict__ sumsq,
                            unsigned short* __restrict__ Xt) {
    __shared__ float tile[64][129];               // stride 129: read-side 2-way (free)
    __shared__ float sred[4][32][8];              // cross-wave stats partials
    const int h  = blockIdx.x;                    // 0..15
    const int by = blockIdx.y;                    // 0..255
    const int n0 = by * 64;
    const int tx = threadIdx.x;
    const int w  = tx >> 6, l = tx & 63;
    const int cq = tx & 31;                       // float4 index within 128-col slice
    const int rq0 = tx >> 5;                      // 0..7

    float4 s  = make_float4(0.f, 0.f, 0.f, 0.f);
    float4 ss = make_float4(0.f, 0.f, 0.f, 0.f);
    #pragma unroll
    for (int it = 0; it < 8; ++it) {
        int r = it * 8 + rq0;
        float4 x = *(const float4*)(X + (size_t)(n0 + r) * HDIM + h * DH + cq * 4);
        s.x += x.x; s.y += x.y; s.z += x.z; s.w += x.w;
        ss.x += x.x * x.x; ss.y += x.y * x.y; ss.z += x.z * x.z; ss.w += x.w * x.w;
        tile[r][cq * 4 + 0] = x.x; tile[r][cq * 4 + 1] = x.y;
        tile[r][cq * 4 + 2] = x.z; tile[r][cq * 4 + 3] = x.w;
    }
    // lanes l and l+32 share the same column quad
    s.x += __shfl_down(s.x, 32);  s.y += __shfl_down(s.y, 32);
    s.z += __shfl_down(s.z, 32);  s.w += __shfl_down(s.w, 32);
    ss.x += __shfl_down(ss.x, 32); ss.y += __shfl_down(ss.y, 32);
    ss.z += __shfl_down(ss.z, 32); ss.w += __shfl_down(ss.w, 32);
    if (l < 32) {
        sred[w][l][0] = s.x;  sred[w][l][1] = s.y;
        sred[w][l][2] = s.z;  sred[w][l][3] = s.w;
        sred[w][l][4] = ss.x; sred[w][l][5] = ss.y;
        sred[w][l][6] = ss.z; sred[w][l][7] = ss.w;
    }
    __syncthreads();
    if (tx < 32) {                                // wave 0 finishes stats: 256 atomics/block
        float a0 = 0.f, a1 = 0.f, a2 = 0.f, a3 = 0.f;
        float b0 = 0.f, b1 = 0.f, b2 = 0.f, b3 = 0.f;
        #pragma unroll
        for (int w2 = 0; w2 < 4; ++w2) {
            a0 += sred[w2][tx][0]; a1 += sred[w2][tx][1];
            a2 += sred[w2][tx][2]; a3 += sred[w2][tx][3];
            b0 += sred[w2][tx][4]; b1 += sred[w2][tx][5];
            b2 += sred[w2][tx][6]; b3 += sred[w2][tx][7];
        }
        int c = h * DH + tx * 4;
        atomicAdd(&sum[c + 0], a0);  atomicAdd(&sum[c + 1], a1);
        atomicAdd(&sum[c + 2], a2);  atomicAdd(&sum[c + 3], a3);
        atomicAdd(&sumsq[c + 0], b0); atomicAdd(&sumsq[c + 1], b1);
        atomicAdd(&sumsq[c + 2], b2); atomicAdd(&sumsq[c + 3], b3);
    }
    // transpose write: 1024 16B-chunks; per wave-instruction 1 KB contiguous
    unsigned short* panel = Xt + ((size_t)h * NKT + by) * (PANEL_BYTES / 2);
    #pragma unroll
    for (int it = 0; it < 4; ++it) {
        int q = it * 256 + tx;
        int c = q >> 3, o = q & 7;                // chunk (c, tokens 8o..8o+7)
        unsigned short v[8];
        #pragma unroll
        for (int m = 0; m < 8; ++m) v[m] = f2bf(tile[o * 8 + m][c]);
        uint4 pk;
        pk.x = (unsigned)v[0] | ((unsigned)v[1] << 16);
        pk.y = (unsigned)v[2] | ((unsigned)v[3] << 16);
        pk.z = (unsigned)v[4] | ((unsigned)v[5] << 16);
        pk.w = (unsigned)v[6] | ((unsigned)v[7] << 16);
        *(uint4*)(panel + c * 64 + o * 8) = pk;
    }
}

// ---------------------------------------------------------------- pass 2: mu / rinv
__global__ void finalize_kernel(const float* __restrict__ sum, const float* __restrict__ sumsq,
                                float* __restrict__ mu, float* __restrict__ rinv) {
    int c = blockIdx.x * 256 + threadIdx.x;       // grid 8 x 256 = 2048
    float m = sum[c] * (1.f / (float)N_TOK);
    float var = (sumsq[c] - (float)N_TOK * m * m) * (1.f / (float)(N_TOK - 1));
    var = fmaxf(var, 0.f);
    mu[c]   = m;
    rinv[c] = 1.f / (sqrtf(var) + 1e-8f);
}

// ---------------------------------------------------------------- pass 3: pairwise raw Gram via MFMA
__device__ __forceinline__ void gload16(const void* gsrc, void* ldst) {
    __builtin_amdgcn_global_load_lds(
        (const __attribute__((address_space(1))) unsigned int*)gsrc,
        (__attribute__((address_space(3))) unsigned int*)ldst,
        16, 0, 0);
}

__global__ __launch_bounds__(256, 4)
void gram_kernel(const unsigned short* __restrict__ Xt, float* __restrict__ pairC) {
    const int kc = blockIdx.x;                    // K-chunk 0..7
    const int p  = blockIdx.y;                    // pair 0..119
    int i = 0, rem = p;
    while (rem >= NH - 1 - i) { rem -= NH - 1 - i; ++i; }
    const int j = i + 1 + rem;

    __shared__ alignas(16) unsigned short ldsA[128 * 64];   // 16 KB (one panel)
    __shared__ alignas(16) unsigned short ldsB[128 * 64];   // 16 KB

    const int tx = threadIdx.x;
    const int w  = tx >> 6, l = tx & 63;
    const int wm = w >> 1, wn = w & 1;            // 2x2 wave grid over 128x128
    const int l15 = l & 15, quad = l >> 4;

    // Staging: panel = 128 rows x 8 chunks of 16B; XOR swizzle at SOURCE offset
    unsigned int goff[4];
    int ldsOff[4];
    #pragma unroll
    for (int s = 0; s < 4; ++s) {
        int cfl = s * 256 + tx;
        int r = cfl >> 3, cl = cfl & 7;
        int cg = cl ^ (r & 7);
        goff[s]   = (unsigned int)(r * 128 + cg * 16);      // byte offset in panel
        ldsOff[s] = s * 4096 + w * 1024;          // wave-uniform LDS base per issue
    }
    const char* Abase = (const char*)Xt + ((size_t)i * NKT + (size_t)kc * KT_PER_CHUNK) * PANEL_BYTES;
    const char* Bbase = (const char*)Xt + ((size_t)j * NKT + (size_t)kc * KT_PER_CHUNK) * PANEL_BYTES;

    f32x4 acc[4][4];
    #pragma unroll
    for (int mi = 0; mi < 4; ++mi)
        #pragma unroll
        for (int ni = 0; ni < 4; ++ni)
            acc[mi][ni] = (f32x4){0.f, 0.f, 0.f, 0.f};

    const int sw = (l15 & 7);
    for (int kt = 0; kt < KT_PER_CHUNK; ++kt) {
        const char* pa = Abase + (size_t)kt * PANEL_BYTES;
        const char* pb = Bbase + (size_t)kt * PANEL_BYTES;
        #pragma unroll
        for (int s = 0; s < 4; ++s)
            gload16(pa + goff[s], (char*)ldsA + ldsOff[s]);
        #pragma unroll
        for (int s = 0; s < 4; ++s)
            gload16(pb + goff[s], (char*)ldsB + ldsOff[s]);
        __syncthreads();

        #pragma unroll
        for (int kh = 0; kh < 2; ++kh) {
            const int q0 = kh * 4 + quad;
            const int c8 = q0 ^ sw;
            bf16x8 a[4], b[4];
            #pragma unroll
            for (int mi = 0; mi < 4; ++mi) {
                int r = wm * 64 + mi * 16 + l15;
                a[mi] = *(const bf16x8*)(ldsA + (r * 8 + c8) * 8);
            }
            #pragma unroll
            for (int ni = 0; ni < 4; ++ni) {
                int r = wn * 64 + ni * 16 + l15;
                b[ni] = *(const bf16x8*)(ldsB + (r * 8 + c8) * 8);
            }
            #pragma unroll
            for (int mi = 0; mi < 4; ++mi)
                #pragma unroll
                for (int ni = 0; ni < 4; ++ni)
                    acc[mi][ni] = __builtin_amdgcn_mfma_f32_16x16x32_bf16(
                        a[mi], b[ni], acc[mi][ni], 0, 0, 0);
        }
        __syncthreads();
    }

    // Epilogue: partial raw Gram -> atomic accumulate (KCHUNKS contenders/address)
    float* pc = pairC + (size_t)p * (DH * DH);
    #pragma unroll
    for (int mi = 0; mi < 4; ++mi)
        #pragma unroll
        for (int ni = 0; ni < 4; ++ni)
            #pragma unroll
            for (int r = 0; r < 4; ++r) {
                int row = wm * 64 + mi * 16 + quad * 4 + r;  // d (head-i dim)
                int col = wn * 64 + ni * 16 + l15;           // e (head-j dim)
                atomicAdd(&pc[row * DH + col], acc[mi][ni][r]);
            }
}

// ---------------------------------------------------------------- pass 4: per-pair loss w/ normalization correction
__global__ void pair_reduce_kernel(const float* __restrict__ pairC, const float* __restrict__ G,
                                   const float* __restrict__ mu, const float* __restrict__ rinv,
                                   float* __restrict__ lsum) {
    int p = blockIdx.x;
    int i = 0, rem = p;
    while (rem >= NH - 1 - i) { rem -= NH - 1 - i; ++i; }
    int j = i + 1 + rem;
    __shared__ float smui[DH], smuj[DH], sri[DH], srj[DH];
    if (threadIdx.x < DH) {
        smui[threadIdx.x] = mu[i * DH + threadIdx.x];
        smuj[threadIdx.x] = mu[j * DH + threadIdx.x];
        sri[threadIdx.x]  = rinv[i * DH + threadIdx.x];
        srj[threadIdx.x]  = rinv[j * DH + threadIdx.x];
    }
    __syncthreads();
    const float invN = 1.f / (float)N_TOK;
    const float* pc = pairC + (size_t)p * (DH * DH);
    float s = 0.f;
    for (int idx = threadIdx.x; idx < DH * DH; idx += 256) {
        int d = idx >> 7, e = idx & 127;
        float cn = (pc[idx] * invN - smui[d] * smuj[e]) * sri[d] * srj[e];
        float diff = cn - ((d == e) ? 1.f : 0.f);
        s += diff * diff;
    }
    for (int o = 32; o; o >>= 1) s += __shfl_down(s, o);
    __shared__ float red[4];
    if ((threadIdx.x & 63) == 0) red[threadIdx.x >> 6] = s;
    __syncthreads();
    if (threadIdx.x == 0) {
        float t = red[0] + red[1] + red[2] + red[3];
        float x = -15.99f * (G[i * NH + j] - 0.0f);
        float sp = (x > 20.f) ? x : log1pf(expf(x));
        float wgt = 0.929f + (1.f - 0.929f) * sp;
        atomicAdd(lsum, wgt * t);
    }
}

__global__ void final_kernel(const float* __restrict__ lsum, float* __restrict__ out) {
    if (threadIdx.x == 0) out[0] = lsum[0] * (1.f / (float)NPAIRS);
}

// ---------------------------------------------------------------- launcher
extern "C" void kernel_launch(void* const* d_in, const int* in_sizes, int n_in,
                              void* d_out, int out_size, void* d_ws, size_t ws_size,
                              hipStream_t stream) {
    const float* X = (const float*)d_in[0];
    const float* G = (const float*)d_in[1];
    float* out = (float*)d_out;
    char* ws = (char*)d_ws;

    float*          sum   = (float*)(ws + SUM_OFF);
    float*          sumsq = (float*)(ws + SUMSQ_OFF);
    float*          mu    = (float*)(ws + MU_OFF);
    float*          rinv  = (float*)(ws + RINV_OFF);
    float*          lsum  = (float*)(ws + LSUM_OFF);
    float*          pairC = (float*)(ws + PC_OFF);
    unsigned short* Xt    = (unsigned short*)(ws + XT_OFF);

    hipMemsetAsync(ws + SUM_OFF, 0, 16384, stream);                     // sum+sumsq
    hipMemsetAsync(ws + LSUM_OFF, 0, 4, stream);
    hipMemsetAsync(ws + PC_OFF, 0, (size_t)NPAIRS * DH * DH * 4, stream);

    stats_transpose_kernel<<<dim3(16, 256), 256, 0, stream>>>(X, sum, sumsq, Xt);
    finalize_kernel<<<8, 256, 0, stream>>>(sum, sumsq, mu, rinv);
    gram_kernel<<<dim3(KCHUNKS, NPAIRS), 256, 0, stream>>>(Xt, pairC);
    pair_reduce_kernel<<<NPAIRS, 256, 0, stream>>>(pairC, G, mu, rinv, lsum);
    final_kernel<<<1, 64, 0, stream>>>(lsum, out);
}

// Round 4
// 296.980 us; speedup vs baseline: 1.3649x; 1.0651x over previous
//
#include <hip/hip_runtime.h>
#include <hip/hip_bf16.h>

// Problem constants
#define N_TOK   16384      // B*T
#define HDIM    2048       // H*d_h
#define NH      16
#define DH      128
#define NPAIRS  120
#define KCHUNKS 8
#define NKT     (N_TOK / 64)            // 256 k-tiles of 64 tokens
#define KT_PER_CHUNK (NKT / KCHUNKS)    // 32
#define PANEL_BYTES 8192                // 128 c-rows x 64 tokens x 1B (fp8)

// Workspace layout (bytes) — total ~41.5 MB
#define SUM_OFF    0u
#define SUMSQ_OFF  8192u
#define MU_OFF     16384u
#define RINV_OFF   24576u
#define PC_OFF     36864u                     // 120*128*128 f32 = 7,864,320 B
#define XT_OFF     7901184u                   // 2048*16384 fp8 = 33,554,432 B

typedef float     f32x4 __attribute__((ext_vector_type(4)));
typedef long long i64t;

// ---------------------------------------------------------------- fp8 e4m3 pack
#if __has_builtin(__builtin_amdgcn_cvt_pk_fp8_f32)
__device__ __forceinline__ unsigned pk4_fp8(float a, float b, float c, float d) {
    int w = __builtin_amdgcn_cvt_pk_fp8_f32(a, b, 0, false);   // bytes 0,1
    w = __builtin_amdgcn_cvt_pk_fp8_f32(c, d, w, true);        // bytes 2,3
    return (unsigned)w;
}
#else
__device__ __forceinline__ unsigned char f2e4m3_sw(float f) {
    unsigned u = __float_as_uint(f);
    unsigned s = (u >> 24) & 0x80u;
    unsigned a = u & 0x7fffffffu;
    if (a >= 0x43e00000u) return (unsigned char)(s | 0x7eu);   // clamp to 448
    if (a < 0x3c800000u) {                                     // |x| < 2^-6: subnormal
        float av = __uint_as_float(a);
        int q = (int)rintf(av * 512.0f);                       // units of 2^-9
        return (unsigned char)(s | (unsigned)q);               // q==8 -> 0x08 == 2^-6 normal
    }
    unsigned lsb = (a >> 20) & 1u;
    a += 0x7ffffu + lsb;                                       // RNE to 3 mantissa bits
    int e8 = (int)(a >> 23) - 120;                             // -127 + 7
    unsigned m = (a >> 20) & 7u;
    return (unsigned char)(s | ((unsigned)e8 << 3) | m);
}
__device__ __forceinline__ unsigned pk4_fp8(float a, float b, float c, float d) {
    return (unsigned)f2e4m3_sw(a) | ((unsigned)f2e4m3_sw(b) << 8) |
           ((unsigned)f2e4m3_sw(c) << 16) | ((unsigned)f2e4m3_sw(d) << 24);
}
#endif

// ---------------------------------------------------------------- pass 1: fused stats + panelized transpose + fp8
// Block = one 8 KB panel: head h, tokens n0..n0+63, all 128 head-dims.
__global__ __launch_bounds__(256)
void stats_transpose_kernel(const float* __restrict__ X,
                            float* __restrict__ sum, float* __restrict__ sumsq,
                            unsigned char* __restrict__ Xt) {
    __shared__ float tile[64][129];               // stride 129
    __shared__ float sred[4][32][8];              // cross-wave stats partials
    const int h  = blockIdx.x;                    // 0..15
    const int by = blockIdx.y;                    // 0..255
    const int n0 = by * 64;
    const int tx = threadIdx.x;
    const int w  = tx >> 6, l = tx & 63;
    const int cq = tx & 31;                       // float4 index within 128-col slice
    const int rq0 = tx >> 5;                      // 0..7

    float4 s  = make_float4(0.f, 0.f, 0.f, 0.f);
    float4 ss = make_float4(0.f, 0.f, 0.f, 0.f);
    #pragma unroll
    for (int it = 0; it < 8; ++it) {
        int r = it * 8 + rq0;
        float4 x = *(const float4*)(X + (size_t)(n0 + r) * HDIM + h * DH + cq * 4);
        s.x += x.x; s.y += x.y; s.z += x.z; s.w += x.w;
        ss.x += x.x * x.x; ss.y += x.y * x.y; ss.z += x.z * x.z; ss.w += x.w * x.w;
        tile[r][cq * 4 + 0] = x.x; tile[r][cq * 4 + 1] = x.y;
        tile[r][cq * 4 + 2] = x.z; tile[r][cq * 4 + 3] = x.w;
    }
    s.x += __shfl_down(s.x, 32);  s.y += __shfl_down(s.y, 32);
    s.z += __shfl_down(s.z, 32);  s.w += __shfl_down(s.w, 32);
    ss.x += __shfl_down(ss.x, 32); ss.y += __shfl_down(ss.y, 32);
    ss.z += __shfl_down(ss.z, 32); ss.w += __shfl_down(ss.w, 32);
    if (l < 32) {
        sred[w][l][0] = s.x;  sred[w][l][1] = s.y;
        sred[w][l][2] = s.z;  sred[w][l][3] = s.w;
        sred[w][l][4] = ss.x; sred[w][l][5] = ss.y;
        sred[w][l][6] = ss.z; sred[w][l][7] = ss.w;
    }
    __syncthreads();
    if (tx < 32) {                                // wave 0 finishes stats
        float a0 = 0.f, a1 = 0.f, a2 = 0.f, a3 = 0.f;
        float b0 = 0.f, b1 = 0.f, b2 = 0.f, b3 = 0.f;
        #pragma unroll
        for (int w2 = 0; w2 < 4; ++w2) {
            a0 += sred[w2][tx][0]; a1 += sred[w2][tx][1];
            a2 += sred[w2][tx][2]; a3 += sred[w2][tx][3];
            b0 += sred[w2][tx][4]; b1 += sred[w2][tx][5];
            b2 += sred[w2][tx][6]; b3 += sred[w2][tx][7];
        }
        int c = h * DH + tx * 4;
        atomicAdd(&sum[c + 0], a0);  atomicAdd(&sum[c + 1], a1);
        atomicAdd(&sum[c + 2], a2);  atomicAdd(&sum[c + 3], a3);
        atomicAdd(&sumsq[c + 0], b0); atomicAdd(&sumsq[c + 1], b1);
        atomicAdd(&sumsq[c + 2], b2); atomicAdd(&sumsq[c + 3], b3);
    }
    // transpose write: 512 16B-chunks (one panel), contiguous per wave-instruction
    unsigned char* panel = Xt + ((size_t)h * NKT + by) * PANEL_BYTES;
    #pragma unroll
    for (int it = 0; it < 2; ++it) {
        int q = it * 256 + tx;
        int c = q >> 2, o = q & 3;                // chunk = (dim c, tokens 16o..16o+15)
        uint4 pk;
        pk.x = pk4_fp8(tile[o*16+ 0][c], tile[o*16+ 1][c], tile[o*16+ 2][c], tile[o*16+ 3][c]);
        pk.y = pk4_fp8(tile[o*16+ 4][c], tile[o*16+ 5][c], tile[o*16+ 6][c], tile[o*16+ 7][c]);
        pk.z = pk4_fp8(tile[o*16+ 8][c], tile[o*16+ 9][c], tile[o*16+10][c], tile[o*16+11][c]);
        pk.w = pk4_fp8(tile[o*16+12][c], tile[o*16+13][c], tile[o*16+14][c], tile[o*16+15][c]);
        *(uint4*)(panel + c * 64 + o * 16) = pk;
    }
}

// ---------------------------------------------------------------- pass 2: mu / rinv
__global__ void finalize_kernel(const float* __restrict__ sum, const float* __restrict__ sumsq,
                                float* __restrict__ mu, float* __restrict__ rinv) {
    int c = blockIdx.x * 256 + threadIdx.x;       // grid 8 x 256 = 2048
    float m = sum[c] * (1.f / (float)N_TOK);
    float var = (sumsq[c] - (float)N_TOK * m * m) * (1.f / (float)(N_TOK - 1));
    var = fmaxf(var, 0.f);
    mu[c]   = m;
    rinv[c] = 1.f / (sqrtf(var) + 1e-8f);
}

// ---------------------------------------------------------------- pass 3: pairwise raw Gram via fp8 MFMA
__device__ __forceinline__ void gload16(const void* gsrc, void* ldst) {
    __builtin_amdgcn_global_load_lds(
        (const __attribute__((address_space(1))) unsigned int*)gsrc,
        (__attribute__((address_space(3))) unsigned int*)ldst,
        16, 0, 0);
}

__global__ __launch_bounds__(256, 4)
void gram_kernel(const unsigned char* __restrict__ Xt, float* __restrict__ pairC) {
    const int kc = blockIdx.x;                    // K-chunk 0..7 -> XCD kc (linear%8)
    const int p  = blockIdx.y;                    // pair 0..119
    int i = 0, rem = p;
    while (rem >= NH - 1 - i) { rem -= NH - 1 - i; ++i; }
    const int j = i + 1 + rem;

    __shared__ alignas(16) unsigned char ldsA[PANEL_BYTES];   // 8 KB
    __shared__ alignas(16) unsigned char ldsB[PANEL_BYTES];   // 8 KB

    const int tx = threadIdx.x;
    const int w  = tx >> 6, l = tx & 63;
    const int wm = w >> 1, wn = w & 1;            // 2x2 wave grid over 128x128
    const int l15 = l & 15, quad = l >> 4;

    // Staging: panel = 128 rows x 4 chunks of 16B; chunk swizzle cc = cl ^ ((r>>1)&3)
    // (keeps 16B chunks intact; equals 8B-unit swizzle u' = u ^ (r&6))
    unsigned int goff[2];
    int ldsOff[2];
    #pragma unroll
    for (int s = 0; s < 2; ++s) {
        int cfl = s * 256 + tx;
        int r = cfl >> 2, cl = cfl & 3;
        int cc = cl ^ ((r >> 1) & 3);
        goff[s]   = (unsigned int)(r * 64 + cc * 16);
        ldsOff[s] = s * 4096 + w * 1024;          // wave-uniform LDS base per issue
    }
    const char* Abase = (const char*)Xt + ((size_t)i * NKT + (size_t)kc * KT_PER_CHUNK) * PANEL_BYTES;
    const char* Bbase = (const char*)Xt + ((size_t)j * NKT + (size_t)kc * KT_PER_CHUNK) * PANEL_BYTES;

    f32x4 acc[4][4];
    #pragma unroll
    for (int mi = 0; mi < 4; ++mi)
        #pragma unroll
        for (int ni = 0; ni < 4; ++ni)
            acc[mi][ni] = (f32x4){0.f, 0.f, 0.f, 0.f};

    const int usw = l15 & 6;                      // row-dependent unit swizzle (rows within
                                                  // a frag read differ by 16 -> r&6 == l15&6)
    for (int kt = 0; kt < KT_PER_CHUNK; ++kt) {
        const char* pa = Abase + (size_t)kt * PANEL_BYTES;
        const char* pb = Bbase + (size_t)kt * PANEL_BYTES;
        gload16(pa + goff[0], (char*)ldsA + ldsOff[0]);
        gload16(pa + goff[1], (char*)ldsA + ldsOff[1]);
        gload16(pb + goff[0], (char*)ldsB + ldsOff[0]);
        gload16(pb + goff[1], (char*)ldsB + ldsOff[1]);
        __syncthreads();

        #pragma unroll
        for (int kh = 0; kh < 2; ++kh) {          // two K=32 fp8 MFMA steps per 64-token tile
            const int u = (kh * 4 + quad) ^ usw;  // swizzled 8B unit
            i64t a[4], b[4];
            #pragma unroll
            for (int mi = 0; mi < 4; ++mi) {
                int r = wm * 64 + mi * 16 + l15;
                a[mi] = *(const i64t*)(ldsA + r * 64 + u * 8);
            }
            #pragma unroll
            for (int ni = 0; ni < 4; ++ni) {
                int r = wn * 64 + ni * 16 + l15;
                b[ni] = *(const i64t*)(ldsB + r * 64 + u * 8);
            }
            #pragma unroll
            for (int mi = 0; mi < 4; ++mi)
                #pragma unroll
                for (int ni = 0; ni < 4; ++ni)
                    acc[mi][ni] = __builtin_amdgcn_mfma_f32_16x16x32_fp8_fp8(
                        a[mi], b[ni], acc[mi][ni], 0, 0, 0);
        }
        __syncthreads();
    }

    // Epilogue: partial raw Gram -> atomic accumulate (KCHUNKS contenders/address)
    float* pc = pairC + (size_t)p * (DH * DH);
    #pragma unroll
    for (int mi = 0; mi < 4; ++mi)
        #pragma unroll
        for (int ni = 0; ni < 4; ++ni)
            #pragma unroll
            for (int r = 0; r < 4; ++r) {
                int row = wm * 64 + mi * 16 + quad * 4 + r;  // d (head-i dim)
                int col = wn * 64 + ni * 16 + l15;           // e (head-j dim)
                atomicAdd(&pc[row * DH + col], acc[mi][ni][r]);
            }
}

// ---------------------------------------------------------------- pass 4: per-pair loss + final accumulate
__global__ void pair_reduce_kernel(const float* __restrict__ pairC, const float* __restrict__ G,
                                   const float* __restrict__ mu, const float* __restrict__ rinv,
                                   float* __restrict__ out) {
    int p = blockIdx.x;
    int i = 0, rem = p;
    while (rem >= NH - 1 - i) { rem -= NH - 1 - i; ++i; }
    int j = i + 1 + rem;
    __shared__ float smui[DH], smuj[DH], sri[DH], srj[DH];
    if (threadIdx.x < DH) {
        smui[threadIdx.x] = mu[i * DH + threadIdx.x];
        smuj[threadIdx.x] = mu[j * DH + threadIdx.x];
        sri[threadIdx.x]  = rinv[i * DH + threadIdx.x];
        srj[threadIdx.x]  = rinv[j * DH + threadIdx.x];
    }
    __syncthreads();
    const float invN = 1.f / (float)N_TOK;
    const float* pc = pairC + (size_t)p * (DH * DH);
    float s = 0.f;
    for (int idx = threadIdx.x; idx < DH * DH; idx += 256) {
        int d = idx >> 7, e = idx & 127;
        float cn = (pc[idx] * invN - smui[d] * smuj[e]) * sri[d] * srj[e];
        float diff = cn - ((d == e) ? 1.f : 0.f);
        s += diff * diff;
    }
    for (int o = 32; o; o >>= 1) s += __shfl_down(s, o);
    __shared__ float red[4];
    if ((threadIdx.x & 63) == 0) red[threadIdx.x >> 6] = s;
    __syncthreads();
    if (threadIdx.x == 0) {
        float t = red[0] + red[1] + red[2] + red[3];
        float x = -15.99f * (G[i * NH + j] - 0.0f);
        float sp = (x > 20.f) ? x : log1pf(expf(x));
        float wgt = 0.929f + (1.f - 0.929f) * sp;
        atomicAdd(out, wgt * t * (1.f / (float)NPAIRS));
    }
}

// ---------------------------------------------------------------- launcher
extern "C" void kernel_launch(void* const* d_in, const int* in_sizes, int n_in,
                              void* d_out, int out_size, void* d_ws, size_t ws_size,
                              hipStream_t stream) {
    const float* X = (const float*)d_in[0];
    const float* G = (const float*)d_in[1];
    float* out = (float*)d_out;
    char* ws = (char*)d_ws;

    float*         sum   = (float*)(ws + SUM_OFF);
    float*         sumsq = (float*)(ws + SUMSQ_OFF);
    float*         mu    = (float*)(ws + MU_OFF);
    float*         rinv  = (float*)(ws + RINV_OFF);
    float*         pairC = (float*)(ws + PC_OFF);
    unsigned char* Xt    = (unsigned char*)(ws + XT_OFF);

    hipMemsetAsync(ws + SUM_OFF, 0, 16384, stream);                     // sum+sumsq
    hipMemsetAsync(ws + PC_OFF, 0, (size_t)NPAIRS * DH * DH * 4, stream);
    hipMemsetAsync(d_out, 0, 4, stream);

    stats_transpose_kernel<<<dim3(16, 256), 256, 0, stream>>>(X, sum, sumsq, Xt);
    finalize_kernel<<<8, 256, 0, stream>>>(sum, sumsq, mu, rinv);
    gram_kernel<<<dim3(KCHUNKS, NPAIRS), 256, 0, stream>>>(Xt, pairC);
    pair_reduce_kernel<<<NPAIRS, 256, 0, stream>>>(pairC, G, mu, rinv, out);
}